// Round 16
// baseline (143.938 us; speedup 1.0000x reference)
//
#include <hip/hip_runtime.h>
#include <math.h>

#define BATCH   65536
#define N_IN    784
#define DD      10
#define NB      10
#define SD      100
#define N_OUTS  10
#define TILES   16
#define ROWST   16
#define XSTRIDE 1616   // bf16 row stride bytes (404 dwords == 20 mod 32 -> benign banks)
#define XBUFB   (16 * XSTRIDE)

typedef float  f32x4  __attribute__((ext_vector_type(4)));
typedef short  bf16x8 __attribute__((ext_vector_type(8)));

// ws float offsets
#define WTF_F 0        // bf16 [25 K][8 ct][512]  frag-linear padded Wt      (51200 f)
#define WDF_F 51200    // bf16 [4 kk][8 ct][512]  frag-linear padded Wd_eff  (8192 f)
#define WOF_F 59392    // bf16 [4 kk][512]        frag-linear Wo_eff A-frags (1024 f)
#define BD_F  60416    // f32 [128] bd_eff zero-padded
#define BL_F  60544    // f32 [16] blog

__device__ __forceinline__ short f2bf(float f) {
    unsigned u = __builtin_bit_cast(unsigned, f);
    unsigned r = u + 0x7fffu + ((u >> 16) & 1u);   // RNE
    return (short)(r >> 16);
}

#define BAR_LGKM() do {                                          \
    asm volatile("s_waitcnt lgkmcnt(0)" ::: "memory");           \
    __builtin_amdgcn_s_barrier();                                \
    __builtin_amdgcn_sched_barrier(0); } while (0)

// ---------------- fused prep: block 0 = gate path + mask-dependent tables;
// ----------------             blocks 1..256 = mask-independent Wt table ----------------
__global__ __launch_bounds__(1024) void prep_kernel(
                             const float* __restrict__ x,
                             const float* __restrict__ W_in,
                             const float* __restrict__ b_in,
                             const float* __restrict__ W_gate,
                             const float* __restrict__ b_gate,
                             const float* __restrict__ W_data,
                             const float* __restrict__ b_data,
                             const float* __restrict__ W_out,
                             const float* __restrict__ b_out,
                             float* __restrict__ out,
                             float* __restrict__ ws) {
    const int tid = threadIdx.x;

    if (blockIdx.x != 0) {
        short* wtf = (short*)(ws + WTF_F);
        int idx = (int)(blockIdx.x - 1) * 1024 + tid;
        if (idx < 25 * 8 * 512) {
            int K = idx / 4096, rem = idx % 4096;
            int ct = rem / 512, l2 = rem % 512;
            int l = l2 >> 3, e = l2 & 7;
            int r = l & 15, g = l >> 4;
            int c = 16 * ct + r, k = K * 32 + g * 8 + e;
            float v = (c < SD && k < N_IN)
                          ? W_in[(c / DD) * (N_IN * DD) + k * DD + (c % DD)] : 0.f;
            wtf[idx] = f2bf(v);
        }
        return;
    }

    __shared__ float a0r0[SD];
    __shared__ float mask_l[SD];
    __shared__ float ao_l[NB];

    if (tid < 800) {                     // acts0 row 0, 8-way k-split + shfl
        int c = tid >> 3, h = tid & 7;
        int s = c / DD, d = c % DD;
        const float* wcol = W_in + s * (N_IN * DD) + d;
        float acc = 0.f;
        int i0 = h * 98;
        #pragma unroll 14
        for (int i = i0; i < i0 + 98; ++i)
            acc += x[i] * wcol[i * DD];
        acc += __shfl_xor(acc, 1, 64);
        acc += __shfl_xor(acc, 2, 64);
        acc += __shfl_xor(acc, 4, 64);
        if (h == 0) a0r0[c] = fmaxf(acc + b_in[c], 0.f);
    }
    __syncthreads();

    if (tid < SD) {                      // gate[s][t] -> mask
        float g = b_gate[tid];
        int s = tid / DD;
        for (int d = 0; d < DD; ++d)
            g += a0r0[s * DD + d] * W_gate[tid * DD + d];
        mask_l[tid] = (g > 0.f) ? 1.f : 0.f;
    }
    __syncthreads();

    if (tid < NB) {
        float any = 0.f;
        for (int s = 0; s < NB; ++s) any = fmaxf(any, mask_l[s * DD + tid]);
        ao_l[tid] = any;
    }
    if (tid == 0) {
        float sum = 0.f;
        for (int i = 0; i < SD; ++i) sum += mask_l[i];
        out[(long)BATCH * N_OUTS] = sum / 20.0f;          // prob_open_gate
    }
    __syncthreads();

    {   // wdf: mask-folded W_data
        short* wdf = (short*)(ws + WDF_F);
        for (int idx = tid; idx < 4 * 8 * 512; idx += 1024) {
            int kk = idx / 4096, rem = idx % 4096;
            int ct = rem / 512, l2 = rem % 512;
            int l = l2 >> 3, e = l2 & 7;
            int r = l & 15, g = l >> 4;
            int m = 16 * ct + r, k = kk * 32 + g * 8 + e;
            float v = 0.f;
            if (m < SD && k < SD) {
                int t = m / DD, eo = m % DD, s = k / DD, d = k % DD;
                v = mask_l[s * DD + t] * W_data[((s * NB + t) * DD + d) * DD + eo];
            }
            wdf[idx] = f2bf(v);
        }
    }
    {   // wof: any_open-folded W_out
        short* wof = (short*)(ws + WOF_F);
        for (int idx = tid; idx < 4 * 512; idx += 1024) {
            int kk = idx / 512, l2 = idx % 512;
            int l = l2 >> 3, e = l2 & 7;
            int o = l & 15, g = l >> 4;
            int te = kk * 32 + g * 8 + e;
            float v = 0.f;
            if (o < 10 && te < SD) {
                int t = te / DD, eo = te % DD;
                v = ao_l[t] * W_out[(t * DD + eo) * N_OUTS + o];
            }
            wof[idx] = f2bf(v);
        }
    }
    if (tid < 128) {                     // bd_eff padded
        float v = 0.f;
        if (tid < SD) {
            int t = tid / DD, e = tid % DD;
            for (int s = 0; s < NB; ++s)
                v += mask_l[s * DD + t] * b_data[(s * NB + t) * DD + e];
        }
        ws[BD_F + tid] = v;
    }
    if (tid < N_OUTS) {                  // blog
        float v = 0.f;
        for (int t = 0; t < NB; ++t) v += ao_l[t] * b_out[t * N_OUTS + tid];
        ws[BL_F + tid] = v;
    }
}

// ---------------- main: producer/consumer waves ----------------
// 256 blocks x 768 thr = 12 waves: waves 0-7 compute (1 ct each, wt in regs,
// ZERO global loads in loop); waves 8-11 stream x (reg-staged, full-period
// in-flight). 2 barriers/tile; vmcnt waits land only on producer waves.
__global__ __launch_bounds__(768, 3) void main_kernel(
        const float* __restrict__ x,
        const float* __restrict__ b_in,
        const float* __restrict__ ws,
        float* __restrict__ out) {
    __shared__ __align__(16) unsigned char xb16[2][XBUFB];   // 51.7 KB
    __shared__ __align__(16) short a0b[16 * 136];
    __shared__ __align__(16) short a1b[16 * 136];
    __shared__ __align__(16) short wdL[4 * 8 * 512];         // 32 KB
    __shared__ __align__(16) short woL[4 * 512];             // 4 KB

    const int tid  = threadIdx.x;
    const int w    = tid >> 6;
    const int lane = tid & 63;
    const int g    = lane >> 4;
    const int r    = lane & 15;
    const size_t rowbase = (size_t)blockIdx.x * (TILES * ROWST);
    const float4* xblk = (const float4*)(x + rowbase * N_IN);

    const short* wtf = (const short*)(ws + WTF_F);
    const short* wdf = (const short*)(ws + WDF_F);
    const short* wof = (const short*)(ws + WOF_F);

    // ---- prologue copies (all 768 threads) ----
    for (int idx = tid; idx < 4 * 8 * 512; idx += 768) wdL[idx] = wdf[idx];
    for (int idx = tid; idx < 4 * 512; idx += 768)     woL[idx] = wof[idx];
    for (int i = tid; i < 192; i += 768) {               // zero pad cols 784..807
        int buf = i / 96, rem = i - buf * 96;
        int row = rem / 6, p = rem - row * 6;
        *(uint2*)(&xb16[buf][0] + row * XSTRIDE + 1568 + p * 8) = make_uint2(0u, 0u);
    }

    // ---- consumer one-time state ----
    bf16x8 wt[25];
    float bi[4], bd[4], blv[4];
    if (w < 8) {
        #pragma unroll
        for (int K = 0; K < 25; ++K)
            wt[K] = *(const bf16x8*)(wtf + (K * 8 + w) * 512 + lane * 8);
        #pragma unroll
        for (int j = 0; j < 4; ++j) {
            int c = 16 * w + 4 * g + j;
            bi[j] = (c < SD) ? b_in[c] : 0.f;
            bd[j] = ws[BD_F + c];
            int o = 4 * g + j;
            blv[j] = (o < 10) ? ws[BL_F + o] : 0.f;
        }
    }

    // ---- producer one-time state ----
    const int ptid = (w >= 8) ? (tid - 512) : 0;         // 0..255
    int loff[13];
    float4 xr[13];
    if (w >= 8) {
        #pragma unroll
        for (int q = 0; q < 13; ++q) {
            int idx = ptid + 256 * q;
            if (idx < 3136) {
                int row = idx / 196, col = idx - row * 196;
                loff[q] = row * XSTRIDE + col * 8;
            } else loff[q] = 0;
        }
    }

#define STAGE_LOAD(t) do {                                                     \
    const float4* _s = xblk + (size_t)(t) * 3136;                              \
    _Pragma("unroll")                                                          \
    for (int _q = 0; _q < 13; ++_q) {                                          \
        int _idx = ptid + 256 * _q;                                            \
        if (_idx < 3136) xr[_q] = _s[_idx];                                    \
    }                                                                          \
    __builtin_amdgcn_sched_barrier(0);                                         \
} while (0)

#define STAGE_WRITE(bufp) do {                                                 \
    _Pragma("unroll")                                                          \
    for (int _q = 0; _q < 13; ++_q) {                                          \
        int _idx = ptid + 256 * _q;                                            \
        if (_idx < 3136) {                                                     \
            unsigned _u0, _u1;                                                 \
            asm("v_cvt_pk_bf16_f32 %0, %1, %2"                                 \
                : "=v"(_u0) : "v"(xr[_q].x), "v"(xr[_q].y));                   \
            asm("v_cvt_pk_bf16_f32 %0, %1, %2"                                 \
                : "=v"(_u1) : "v"(xr[_q].z), "v"(xr[_q].w));                   \
            *(uint2*)((bufp) + loff[_q]) = make_uint2(_u0, _u1);               \
        }                                                                      \
    }                                                                          \
} while (0)

    if (w >= 8) {
        STAGE_LOAD(0);
        STAGE_WRITE(&xb16[0][0]);      // compiler inserts the vmcnt wait
        STAGE_LOAD(1);                 // stays in flight across the barrier
    }
    BAR_LGKM();

    for (int t = 0; t < TILES; ++t) {
        const int cur = t & 1;

        // ---- compute waves: phase 2 (no global access, no vmcnt stalls) ----
        if (w < 8) {
            f32x4 acc = (f32x4){0.f, 0.f, 0.f, 0.f};
            const unsigned char* xbr = &xb16[cur][0] + r * XSTRIDE + g * 16;
            #pragma unroll
            for (int K = 0; K < 25; ++K) {
                bf16x8 bf = *(const bf16x8*)(xbr + K * 64);
                acc = __builtin_amdgcn_mfma_f32_16x16x32_bf16(wt[K], bf, acc, 0, 0, 0);
            }
            short* myrow = a0b + r * 136;
            int c0 = 16 * w + 4 * g;
            float v0 = fmaxf(acc[0] + bi[0], 0.f), v1 = fmaxf(acc[1] + bi[1], 0.f);
            float v2 = fmaxf(acc[2] + bi[2], 0.f), v3 = fmaxf(acc[3] + bi[3], 0.f);
            unsigned p01, p23;
            asm("v_cvt_pk_bf16_f32 %0, %1, %2" : "=v"(p01) : "v"(v0), "v"(v1));
            asm("v_cvt_pk_bf16_f32 %0, %1, %2" : "=v"(p23) : "v"(v2), "v"(v3));
            *(uint2*)(myrow + c0) = make_uint2(p01, p23);
        }
        BAR_LGKM();                              // B1: a0b sealed

        if (w < 8) {
            // ---- phase 3a: acts1 = relu(acts0 @ Wd^T + bd), K=128 ----
            f32x4 acc2 = (f32x4){0.f, 0.f, 0.f, 0.f};
            #pragma unroll
            for (int kk = 0; kk < 4; ++kk) {
                bf16x8 af = *(const bf16x8*)(wdL + (kk * 8 + w) * 512 + lane * 8);
                bf16x8 bf = *(const bf16x8*)(a0b + r * 136 + kk * 32 + g * 8);
                acc2 = __builtin_amdgcn_mfma_f32_16x16x32_bf16(af, bf, acc2, 0, 0, 0);
            }
            short* myrow = a1b + r * 136;
            int c0 = 16 * w + 4 * g;
            float v0 = fmaxf(acc2[0] + bd[0], 0.f), v1 = fmaxf(acc2[1] + bd[1], 0.f);
            float v2 = fmaxf(acc2[2] + bd[2], 0.f), v3 = fmaxf(acc2[3] + bd[3], 0.f);
            unsigned p01, p23;
            asm("v_cvt_pk_bf16_f32 %0, %1, %2" : "=v"(p01) : "v"(v0), "v"(v1));
            asm("v_cvt_pk_bf16_f32 %0, %1, %2" : "=v"(p23) : "v"(v2), "v"(v3));
            *(uint2*)(myrow + c0) = make_uint2(p01, p23);
        } else {
            // ---- producer waves: deliver next tile, refill the pipe ----
            if (t + 1 < TILES) STAGE_WRITE(&xb16[cur ^ 1][0]);
            if (t + 2 < TILES) STAGE_LOAD(t + 2);
        }
        BAR_LGKM();                              // B2: a1b + next x buffer sealed

        // ---- phase 3b: logits via MFMA + in-register log_softmax + store ----
        if (w < 8) {
            f32x4 accL = (f32x4){0.f, 0.f, 0.f, 0.f};
            #pragma unroll
            for (int kk = 0; kk < 4; ++kk) {
                bf16x8 af = *(const bf16x8*)(woL + kk * 512 + lane * 8);
                bf16x8 bf = *(const bf16x8*)(a1b + r * 136 + kk * 32 + g * 8);
                accL = __builtin_amdgcn_mfma_f32_16x16x32_bf16(af, bf, accL, 0, 0, 0);
            }
            float lgf[4];
            #pragma unroll
            for (int j = 0; j < 4; ++j)
                lgf[j] = (4 * g + j < 10) ? accL[j] + blv[j] : -1e30f;

            float m = fmaxf(fmaxf(lgf[0], lgf[1]), fmaxf(lgf[2], lgf[3]));
            m = fmaxf(m, __shfl_xor(m, 16, 64));
            m = fmaxf(m, __shfl_xor(m, 32, 64));
            float s = expf(lgf[0] - m) + expf(lgf[1] - m)
                    + expf(lgf[2] - m) + expf(lgf[3] - m);
            s += __shfl_xor(s, 16, 64);
            s += __shfl_xor(s, 32, 64);
            float z = m + logf(s);

            if ((r >> 1) == w) {                 // wave w stores rows {2w, 2w+1}
                float* ob = out + (rowbase + (size_t)t * ROWST + r) * N_OUTS + 4 * g;
                if (g < 3) *(float2*)(ob)     = make_float2(lgf[0] - z, lgf[1] - z);
                if (g < 2) *(float2*)(ob + 2) = make_float2(lgf[2] - z, lgf[3] - z);
            }
        }
        // no trailing barrier: a0b rewrite happens after next B1; a1b reads
        // (3b) complete before any wave crosses the next B1.
    }
#undef STAGE_LOAD
#undef STAGE_WRITE
}

extern "C" void kernel_launch(void* const* d_in, const int* in_sizes, int n_in,
                              void* d_out, int out_size, void* d_ws, size_t ws_size,
                              hipStream_t stream) {
    const float* x      = (const float*)d_in[0];
    const float* W_in   = (const float*)d_in[1];
    const float* b_in   = (const float*)d_in[2];
    const float* W_gate = (const float*)d_in[3];
    const float* b_gate = (const float*)d_in[4];
    const float* W_data = (const float*)d_in[5];
    const float* b_data = (const float*)d_in[6];
    const float* W_out  = (const float*)d_in[7];
    const float* b_out  = (const float*)d_in[8];
    float* out = (float*)d_out;
    float* ws  = (float*)d_ws;

    prep_kernel<<<257, 1024, 0, stream>>>(x, W_in, b_in, W_gate, b_gate,
                                          W_data, b_data, W_out, b_out, out, ws);
    main_kernel<<<256, 768, 0, stream>>>(x, b_in, ws, out);
}

// Round 18
// 70.265 us; speedup vs baseline: 2.0485x; 2.0485x over previous
//
#include <hip/hip_runtime.h>
#include <math.h>

#define BATCH   65536
#define N_IN    784
#define DD      10
#define NB      10
#define SD      100
#define N_OUTS  10
#define TILES   16
#define ROWST   16
#define XSTRIDE 1616   // bf16 row stride bytes (404 dwords == 20 mod 32 -> benign banks)
#define XBUFB   (16 * XSTRIDE)

typedef float  f32x4  __attribute__((ext_vector_type(4)));
typedef short  bf16x8 __attribute__((ext_vector_type(8)));

// ws float offsets
#define WTF_F 0        // bf16 [25 K][8 ct][512]  frag-linear padded Wt      (51200 f)
#define WDF_F 51200    // bf16 [4 kk][8 ct][512]  frag-linear padded Wd_eff  (8192 f)
#define WOF_F 59392    // bf16 [4 kk][512]        frag-linear Wo_eff A-frags (1024 f)
#define BD_F  60416    // f32 [128] bd_eff zero-padded
#define BL_F  60544    // f32 [16] blog

__device__ __forceinline__ short f2bf(float f) {
    unsigned u = __builtin_bit_cast(unsigned, f);
    unsigned r = u + 0x7fffu + ((u >> 16) & 1u);   // RNE
    return (short)(r >> 16);
}

#define BAR_LGKM() do {                                          \
    asm volatile("s_waitcnt lgkmcnt(0)" ::: "memory");           \
    __builtin_amdgcn_s_barrier();                                \
    __builtin_amdgcn_sched_barrier(0); } while (0)

// ---------------- fused prep: block 0 = gate path + mask-dependent tables;
// ----------------             blocks 1..256 = mask-independent Wt table ----------------
__global__ __launch_bounds__(1024) void prep_kernel(
                             const float* __restrict__ x,
                             const float* __restrict__ W_in,
                             const float* __restrict__ b_in,
                             const float* __restrict__ W_gate,
                             const float* __restrict__ b_gate,
                             const float* __restrict__ W_data,
                             const float* __restrict__ b_data,
                             const float* __restrict__ W_out,
                             const float* __restrict__ b_out,
                             float* __restrict__ out,
                             float* __restrict__ ws) {
    const int tid = threadIdx.x;

    if (blockIdx.x != 0) {
        short* wtf = (short*)(ws + WTF_F);
        int idx = (int)(blockIdx.x - 1) * 1024 + tid;
        if (idx < 25 * 8 * 512) {
            int K = idx / 4096, rem = idx % 4096;
            int ct = rem / 512, l2 = rem % 512;
            int l = l2 >> 3, e = l2 & 7;
            int r = l & 15, g = l >> 4;
            int c = 16 * ct + r, k = K * 32 + g * 8 + e;
            float v = (c < SD && k < N_IN)
                          ? W_in[(c / DD) * (N_IN * DD) + k * DD + (c % DD)] : 0.f;
            wtf[idx] = f2bf(v);
        }
        return;
    }

    __shared__ float a0r0[SD];
    __shared__ float mask_l[SD];
    __shared__ float ao_l[NB];

    if (tid < 800) {                     // acts0 row 0, 8-way k-split + shfl
        int c = tid >> 3, h = tid & 7;
        int s = c / DD, d = c % DD;
        const float* wcol = W_in + s * (N_IN * DD) + d;
        float acc = 0.f;
        int i0 = h * 98;
        #pragma unroll 14
        for (int i = i0; i < i0 + 98; ++i)
            acc += x[i] * wcol[i * DD];
        acc += __shfl_xor(acc, 1, 64);
        acc += __shfl_xor(acc, 2, 64);
        acc += __shfl_xor(acc, 4, 64);
        if (h == 0) a0r0[c] = fmaxf(acc + b_in[c], 0.f);
    }
    __syncthreads();

    if (tid < SD) {                      // gate[s][t] -> mask
        float g = b_gate[tid];
        int s = tid / DD;
        for (int d = 0; d < DD; ++d)
            g += a0r0[s * DD + d] * W_gate[tid * DD + d];
        mask_l[tid] = (g > 0.f) ? 1.f : 0.f;
    }
    __syncthreads();

    if (tid < NB) {
        float any = 0.f;
        for (int s = 0; s < NB; ++s) any = fmaxf(any, mask_l[s * DD + tid]);
        ao_l[tid] = any;
    }
    if (tid == 0) {
        float sum = 0.f;
        for (int i = 0; i < SD; ++i) sum += mask_l[i];
        out[(long)BATCH * N_OUTS] = sum / 20.0f;          // prob_open_gate
    }
    __syncthreads();

    {   // wdf: mask-folded W_data
        short* wdf = (short*)(ws + WDF_F);
        for (int idx = tid; idx < 4 * 8 * 512; idx += 1024) {
            int kk = idx / 4096, rem = idx % 4096;
            int ct = rem / 512, l2 = rem % 512;
            int l = l2 >> 3, e = l2 & 7;
            int r = l & 15, g = l >> 4;
            int m = 16 * ct + r, k = kk * 32 + g * 8 + e;
            float v = 0.f;
            if (m < SD && k < SD) {
                int t = m / DD, eo = m % DD, s = k / DD, d = k % DD;
                v = mask_l[s * DD + t] * W_data[((s * NB + t) * DD + d) * DD + eo];
            }
            wdf[idx] = f2bf(v);
        }
    }
    {   // wof: any_open-folded W_out
        short* wof = (short*)(ws + WOF_F);
        for (int idx = tid; idx < 4 * 512; idx += 1024) {
            int kk = idx / 512, l2 = idx % 512;
            int l = l2 >> 3, e = l2 & 7;
            int o = l & 15, g = l >> 4;
            int te = kk * 32 + g * 8 + e;
            float v = 0.f;
            if (o < 10 && te < SD) {
                int t = te / DD, eo = te % DD;
                v = ao_l[t] * W_out[(t * DD + eo) * N_OUTS + o];
            }
            wof[idx] = f2bf(v);
        }
    }
    if (tid < 128) {                     // bd_eff padded
        float v = 0.f;
        if (tid < SD) {
            int t = tid / DD, e = tid % DD;
            for (int s = 0; s < NB; ++s)
                v += mask_l[s * DD + t] * b_data[(s * NB + t) * DD + e];
        }
        ws[BD_F + tid] = v;
    }
    if (tid < N_OUTS) {                  // blog
        float v = 0.f;
        for (int t = 0; t < NB; ++t) v += ao_l[t] * b_out[t * N_OUTS + tid];
        ws[BL_F + tid] = v;
    }
}

// ---------------- main: split-K 16-wave blocks (4 waves/SIMD) ----------------
// 256 blocks x 1024 thr = 16 waves. Wave w: ct = w&7, kh = w>>3.
// wt = 13/12 frags per wave (<=52 VGPR) -> fits 128-VGPR cap -> 4 waves/SIMD.
// kh1 waves: upper-K partials + ALL x staging (load at tile top, write B2..B3).
// kh0 waves: lower-K + combine + full 3a/3b tail.
__global__ __launch_bounds__(1024, 4) void main_kernel(
        const float* __restrict__ x,
        const float* __restrict__ b_in,
        const float* __restrict__ ws,
        float* __restrict__ out) {
    __shared__ __align__(16) unsigned char xb16[2][XBUFB];   // 51.7 KB
    __shared__ __align__(16) short a0b[16 * 136];
    __shared__ __align__(16) short a1b[16 * 136];
    __shared__ __align__(16) short wdL[4 * 8 * 512];         // 32 KB
    __shared__ __align__(16) short woL[4 * 512];             // 4 KB
    __shared__ __align__(16) unsigned char pL[8 * 1024];     // 8 KB K-partials

    const int tid  = threadIdx.x;
    const int w    = tid >> 6;
    const int lane = tid & 63;
    const int g    = lane >> 4;
    const int r    = lane & 15;
    const int ct   = w & 7;
    const int kh   = w >> 3;
    const size_t rowbase = (size_t)blockIdx.x * (TILES * ROWST);
    const float4* xblk = (const float4*)(x + rowbase * N_IN);

    const short* wtf = (const short*)(ws + WTF_F);
    const short* wdf = (const short*)(ws + WDF_F);
    const short* wof = (const short*)(ws + WOF_F);

    // ---- prologue LDS copies (all 1024 threads) ----
    for (int idx = tid; idx < 4 * 8 * 512; idx += 1024) wdL[idx] = wdf[idx];
    for (int idx = tid; idx < 4 * 512; idx += 1024)     woL[idx] = wof[idx];
    for (int i = tid; i < 192; i += 1024) {              // zero pad cols 784..807
        int buf = i / 96, rem = i - buf * 96;
        int row = rem / 6, p = rem - row * 6;
        *(uint2*)(&xb16[buf][0] + row * XSTRIDE + 1568 + p * 8) = make_uint2(0u, 0u);
    }

    // ---- weights: split-K frags (kh0: K 0..12, kh1: K 13..24) ----
    bf16x8 wt[13];
    const int k0 = kh * 13;
    #pragma unroll
    for (int i = 0; i < 13; ++i) {
        int K = k0 + i;
        if (K > 24) K = 24;                              // kh1 slot 12 unused (dup)
        wt[i] = *(const bf16x8*)(wtf + (K * 8 + ct) * 512 + lane * 8);
    }
    float bi[4], bd[4], blv[4];
    if (kh == 0) {
        #pragma unroll
        for (int j = 0; j < 4; ++j) {
            int c = 16 * ct + 4 * g + j;
            bi[j] = (c < SD) ? b_in[c] : 0.f;
            bd[j] = ws[BD_F + c];
            int o = 4 * g + j;
            blv[j] = (o < 10) ? ws[BL_F + o] : 0.f;
        }
    }

    // ---- producer (kh1) staging state: 512 threads, 6+1 float4 each ----
    const int ptid = tid - 512;                          // valid for kh1
    int loff[7];
    float4 xr[7];
    if (kh == 1) {
        #pragma unroll
        for (int q = 0; q < 7; ++q) {
            int idx = ptid + 512 * q;
            int row = idx / 196, col = idx - row * 196;
            if (row > 15) { row = 15; col = 0; }         // q=6, ptid>=64: unused
            loff[q] = row * XSTRIDE + col * 8;
        }
    }

#define STAGE_LOAD(t) do {                                                     \
    const float4* _s = xblk + (size_t)(t) * 3136;                              \
    _Pragma("unroll")                                                          \
    for (int _q = 0; _q < 6; ++_q)                                             \
        xr[_q] = _s[ptid + 512 * _q];                                          \
    if (ptid < 64) xr[6] = _s[ptid + 3072];                                    \
    __builtin_amdgcn_sched_barrier(0);                                         \
} while (0)

#define STAGE_WRITE(bufp) do {                                                 \
    _Pragma("unroll")                                                          \
    for (int _q = 0; _q < 6; ++_q) {                                           \
        unsigned _u0, _u1;                                                     \
        asm("v_cvt_pk_bf16_f32 %0, %1, %2"                                     \
            : "=v"(_u0) : "v"(xr[_q].x), "v"(xr[_q].y));                       \
        asm("v_cvt_pk_bf16_f32 %0, %1, %2"                                     \
            : "=v"(_u1) : "v"(xr[_q].z), "v"(xr[_q].w));                       \
        *(uint2*)((bufp) + loff[_q]) = make_uint2(_u0, _u1);                   \
    }                                                                          \
    if (ptid < 64) {                                                           \
        unsigned _u0, _u1;                                                     \
        asm("v_cvt_pk_bf16_f32 %0, %1, %2"                                     \
            : "=v"(_u0) : "v"(xr[6].x), "v"(xr[6].y));                         \
        asm("v_cvt_pk_bf16_f32 %0, %1, %2"                                     \
            : "=v"(_u1) : "v"(xr[6].z), "v"(xr[6].w));                         \
        *(uint2*)((bufp) + loff[6]) = make_uint2(_u0, _u1);                    \
    }                                                                          \
} while (0)

    // ---- prologue: kh1 stages tile 0 ----
    if (kh == 1) {
        STAGE_LOAD(0);
        STAGE_WRITE(&xb16[0][0]);      // compiler inserts the vmcnt wait
    }
    BAR_LGKM();

    for (int t = 0; t < TILES; ++t) {
        const int cur = t & 1;
        if (kh == 1 && t + 1 < TILES) STAGE_LOAD(t + 1);   // issue early

        // ---- phase 2 (split-K): all 16 waves ----
        f32x4 acc = (f32x4){0.f, 0.f, 0.f, 0.f};
        {
            const unsigned char* xbr = &xb16[cur][0] + r * XSTRIDE + g * 16;
            if (kh == 0) {
                #pragma unroll
                for (int i = 0; i < 13; ++i) {
                    bf16x8 bf = *(const bf16x8*)(xbr + i * 64);
                    acc = __builtin_amdgcn_mfma_f32_16x16x32_bf16(wt[i], bf, acc, 0, 0, 0);
                }
            } else {
                #pragma unroll
                for (int i = 0; i < 12; ++i) {
                    bf16x8 bf = *(const bf16x8*)(xbr + (13 + i) * 64);
                    acc = __builtin_amdgcn_mfma_f32_16x16x32_bf16(wt[i], bf, acc, 0, 0, 0);
                }
                *(f32x4*)(pL + ct * 1024 + lane * 16) = acc;   // dump partial
            }
        }
        BAR_LGKM();                              // B1: partials sealed

        if (kh == 0) {
            // ---- combine + bias + relu + cvt -> a0b ----
            f32x4 p = *(const f32x4*)(pL + ct * 1024 + lane * 16);
            short* myrow = a0b + r * 136;
            int c0 = 16 * ct + 4 * g;
            float v0 = fmaxf(acc[0] + p[0] + bi[0], 0.f);
            float v1 = fmaxf(acc[1] + p[1] + bi[1], 0.f);
            float v2 = fmaxf(acc[2] + p[2] + bi[2], 0.f);
            float v3 = fmaxf(acc[3] + p[3] + bi[3], 0.f);
            unsigned p01, p23;
            asm("v_cvt_pk_bf16_f32 %0, %1, %2" : "=v"(p01) : "v"(v0), "v"(v1));
            asm("v_cvt_pk_bf16_f32 %0, %1, %2" : "=v"(p23) : "v"(v2), "v"(v3));
            *(uint2*)(myrow + c0) = make_uint2(p01, p23);
        }
        BAR_LGKM();                              // B2: a0b sealed

        if (kh == 0) {
            // ---- phase 3a: acts1 = relu(acts0 @ Wd^T + bd), K=128 ----
            f32x4 acc2 = (f32x4){0.f, 0.f, 0.f, 0.f};
            #pragma unroll
            for (int kk = 0; kk < 4; ++kk) {
                bf16x8 af = *(const bf16x8*)(wdL + (kk * 8 + ct) * 512 + lane * 8);
                bf16x8 bf = *(const bf16x8*)(a0b + r * 136 + kk * 32 + g * 8);
                acc2 = __builtin_amdgcn_mfma_f32_16x16x32_bf16(af, bf, acc2, 0, 0, 0);
            }
            short* myrow = a1b + r * 136;
            int c0 = 16 * ct + 4 * g;
            float v0 = fmaxf(acc2[0] + bd[0], 0.f), v1 = fmaxf(acc2[1] + bd[1], 0.f);
            float v2 = fmaxf(acc2[2] + bd[2], 0.f), v3 = fmaxf(acc2[3] + bd[3], 0.f);
            unsigned p01, p23;
            asm("v_cvt_pk_bf16_f32 %0, %1, %2" : "=v"(p01) : "v"(v0), "v"(v1));
            asm("v_cvt_pk_bf16_f32 %0, %1, %2" : "=v"(p23) : "v"(v2), "v"(v3));
            *(uint2*)(myrow + c0) = make_uint2(p01, p23);
        } else {
            // ---- producer: deliver next tile into the other buffer ----
            if (t + 1 < TILES) STAGE_WRITE(&xb16[cur ^ 1][0]);
        }
        BAR_LGKM();                              // B3: a1b + next x buffer sealed

        // ---- phase 3b: logits via MFMA + in-register log_softmax + store ----
        if (kh == 0) {
            f32x4 accL = (f32x4){0.f, 0.f, 0.f, 0.f};
            #pragma unroll
            for (int kk = 0; kk < 4; ++kk) {
                bf16x8 af = *(const bf16x8*)(woL + kk * 512 + lane * 8);
                bf16x8 bf = *(const bf16x8*)(a1b + r * 136 + kk * 32 + g * 8);
                accL = __builtin_amdgcn_mfma_f32_16x16x32_bf16(af, bf, accL, 0, 0, 0);
            }
            float lgf[4];
            #pragma unroll
            for (int j = 0; j < 4; ++j)
                lgf[j] = (4 * g + j < 10) ? accL[j] + blv[j] : -1e30f;

            float m = fmaxf(fmaxf(lgf[0], lgf[1]), fmaxf(lgf[2], lgf[3]));
            m = fmaxf(m, __shfl_xor(m, 16, 64));
            m = fmaxf(m, __shfl_xor(m, 32, 64));
            float s = expf(lgf[0] - m) + expf(lgf[1] - m)
                    + expf(lgf[2] - m) + expf(lgf[3] - m);
            s += __shfl_xor(s, 16, 64);
            s += __shfl_xor(s, 32, 64);
            float z = m + logf(s);

            if ((r >> 1) == ct) {                // wave ct stores rows {2ct, 2ct+1}
                float* ob = out + (rowbase + (size_t)t * ROWST + r) * N_OUTS + 4 * g;
                if (g < 3) *(float2*)(ob)     = make_float2(lgf[0] - z, lgf[1] - z);
                if (g < 2) *(float2*)(ob + 2) = make_float2(lgf[2] - z, lgf[3] - z);
            }
        }
        // no trailing barrier: next-tile hazards are sealed by B1/B2/B3 above.
    }
#undef STAGE_LOAD
#undef STAGE_WRITE
}

extern "C" void kernel_launch(void* const* d_in, const int* in_sizes, int n_in,
                              void* d_out, int out_size, void* d_ws, size_t ws_size,
                              hipStream_t stream) {
    const float* x      = (const float*)d_in[0];
    const float* W_in   = (const float*)d_in[1];
    const float* b_in   = (const float*)d_in[2];
    const float* W_gate = (const float*)d_in[3];
    const float* b_gate = (const float*)d_in[4];
    const float* W_data = (const float*)d_in[5];
    const float* b_data = (const float*)d_in[6];
    const float* W_out  = (const float*)d_in[7];
    const float* b_out  = (const float*)d_in[8];
    float* out = (float*)d_out;
    float* ws  = (float*)d_ws;

    prep_kernel<<<257, 1024, 0, stream>>>(x, W_in, b_in, W_gate, b_gate,
                                          W_data, b_data, W_out, b_out, out, ws);
    main_kernel<<<256, 1024, 0, stream>>>(x, b_in, ws, out);
}

// Round 19
// 67.157 us; speedup vs baseline: 2.1433x; 1.0463x over previous
//
#include <hip/hip_runtime.h>
#include <math.h>

#define BATCH   65536
#define N_IN    784
#define DD      10
#define NB      10
#define SD      100
#define N_OUTS  10
#define TILES   16
#define ROWST   16
#define XSTRIDE 1616   // bf16 row stride bytes (404 dwords == 20 mod 32 -> benign banks)
#define XBUFB   (16 * XSTRIDE)

typedef float  f32x4  __attribute__((ext_vector_type(4)));
typedef short  bf16x8 __attribute__((ext_vector_type(8)));

// ws float offsets
#define WTF_F 0        // bf16 [25 K][8 ct][512]  frag-linear padded Wt      (51200 f)
#define WDF_F 51200    // bf16 [4 kk][8 ct][512]  frag-linear padded Wd_eff  (8192 f)
#define WOF_F 59392    // bf16 [4 kk][512]        frag-linear Wo_eff A-frags (1024 f)
#define BD_F  60416    // f32 [128] bd_eff zero-padded
#define BL_F  60544    // f32 [16] blog

__device__ __forceinline__ short f2bf(float f) {
    unsigned u = __builtin_bit_cast(unsigned, f);
    unsigned r = u + 0x7fffu + ((u >> 16) & 1u);   // RNE
    return (short)(r >> 16);
}

#define BAR_LGKM() do {                                          \
    asm volatile("s_waitcnt lgkmcnt(0)" ::: "memory");           \
    __builtin_amdgcn_s_barrier();                                \
    __builtin_amdgcn_sched_barrier(0); } while (0)

// ---------------- fused prep: block 0 = gate path + mask-dependent tables;
// ----------------             blocks 1..256 = mask-independent Wt table ----------------
__global__ __launch_bounds__(1024) void prep_kernel(
                             const float* __restrict__ x,
                             const float* __restrict__ W_in,
                             const float* __restrict__ b_in,
                             const float* __restrict__ W_gate,
                             const float* __restrict__ b_gate,
                             const float* __restrict__ W_data,
                             const float* __restrict__ b_data,
                             const float* __restrict__ W_out,
                             const float* __restrict__ b_out,
                             float* __restrict__ out,
                             float* __restrict__ ws) {
    const int tid = threadIdx.x;

    if (blockIdx.x != 0) {
        short* wtf = (short*)(ws + WTF_F);
        int idx = (int)(blockIdx.x - 1) * 1024 + tid;
        if (idx < 25 * 8 * 512) {
            int K = idx / 4096, rem = idx % 4096;
            int ct = rem / 512, l2 = rem % 512;
            int l = l2 >> 3, e = l2 & 7;
            int r = l & 15, g = l >> 4;
            int c = 16 * ct + r, k = K * 32 + g * 8 + e;
            float v = (c < SD && k < N_IN)
                          ? W_in[(c / DD) * (N_IN * DD) + k * DD + (c % DD)] : 0.f;
            wtf[idx] = f2bf(v);
        }
        return;
    }

    __shared__ float a0r0[SD];
    __shared__ float mask_l[SD];
    __shared__ float ao_l[NB];

    if (tid < 800) {                     // acts0 row 0, 8-way k-split + shfl
        int c = tid >> 3, h = tid & 7;
        int s = c / DD, d = c % DD;
        const float* wcol = W_in + s * (N_IN * DD) + d;
        float acc = 0.f;
        int i0 = h * 98;
        #pragma unroll 14
        for (int i = i0; i < i0 + 98; ++i)
            acc += x[i] * wcol[i * DD];
        acc += __shfl_xor(acc, 1, 64);
        acc += __shfl_xor(acc, 2, 64);
        acc += __shfl_xor(acc, 4, 64);
        if (h == 0) a0r0[c] = fmaxf(acc + b_in[c], 0.f);
    }
    __syncthreads();

    if (tid < SD) {                      // gate[s][t] -> mask
        float g = b_gate[tid];
        int s = tid / DD;
        for (int d = 0; d < DD; ++d)
            g += a0r0[s * DD + d] * W_gate[tid * DD + d];
        mask_l[tid] = (g > 0.f) ? 1.f : 0.f;
    }
    __syncthreads();

    if (tid < NB) {
        float any = 0.f;
        for (int s = 0; s < NB; ++s) any = fmaxf(any, mask_l[s * DD + tid]);
        ao_l[tid] = any;
    }
    if (tid == 0) {
        float sum = 0.f;
        for (int i = 0; i < SD; ++i) sum += mask_l[i];
        out[(long)BATCH * N_OUTS] = sum / 20.0f;          // prob_open_gate
    }
    __syncthreads();

    {   // wdf: mask-folded W_data
        short* wdf = (short*)(ws + WDF_F);
        for (int idx = tid; idx < 4 * 8 * 512; idx += 1024) {
            int kk = idx / 4096, rem = idx % 4096;
            int ct = rem / 512, l2 = rem % 512;
            int l = l2 >> 3, e = l2 & 7;
            int r = l & 15, g = l >> 4;
            int m = 16 * ct + r, k = kk * 32 + g * 8 + e;
            float v = 0.f;
            if (m < SD && k < SD) {
                int t = m / DD, eo = m % DD, s = k / DD, d = k % DD;
                v = mask_l[s * DD + t] * W_data[((s * NB + t) * DD + d) * DD + eo];
            }
            wdf[idx] = f2bf(v);
        }
    }
    {   // wof: any_open-folded W_out
        short* wof = (short*)(ws + WOF_F);
        for (int idx = tid; idx < 4 * 512; idx += 1024) {
            int kk = idx / 512, l2 = idx % 512;
            int l = l2 >> 3, e = l2 & 7;
            int o = l & 15, g = l >> 4;
            int te = kk * 32 + g * 8 + e;
            float v = 0.f;
            if (o < 10 && te < SD) {
                int t = te / DD, eo = te % DD;
                v = ao_l[t] * W_out[(t * DD + eo) * N_OUTS + o];
            }
            wof[idx] = f2bf(v);
        }
    }
    if (tid < 128) {                     // bd_eff padded
        float v = 0.f;
        if (tid < SD) {
            int t = tid / DD, e = tid % DD;
            for (int s = 0; s < NB; ++s)
                v += mask_l[s * DD + t] * b_data[(s * NB + t) * DD + e];
        }
        ws[BD_F + tid] = v;
    }
    if (tid < N_OUTS) {                  // blog
        float v = 0.f;
        for (int t = 0; t < NB; ++t) v += ao_l[t] * b_out[t * N_OUTS + tid];
        ws[BL_F + tid] = v;
    }
}

// ---------------- main: split-K 16 waves, ALL waves stage (4 issuing waves/SIMD) ----------------
// 256 blocks x 1024 thr. Wave w: ct = w&7, kh = w>>3. wt <= 52 VGPR -> 128 cap OK.
// Staging spread over all 1024 threads: 3(+1) float4 each, write post-B1.
__global__ __launch_bounds__(1024, 4) void main_kernel(
        const float* __restrict__ x,
        const float* __restrict__ b_in,
        const float* __restrict__ ws,
        float* __restrict__ out) {
    __shared__ __align__(16) unsigned char xb16[2][XBUFB];   // 51.7 KB
    __shared__ __align__(16) short a0b[16 * 136];
    __shared__ __align__(16) short a1b[16 * 136];
    __shared__ __align__(16) short wdL[4 * 8 * 512];         // 32 KB
    __shared__ __align__(16) short woL[4 * 512];             // 4 KB
    __shared__ __align__(16) unsigned char pL[8 * 1024];     // 8 KB K-partials

    const int tid  = threadIdx.x;
    const int w    = tid >> 6;
    const int lane = tid & 63;
    const int g    = lane >> 4;
    const int r    = lane & 15;
    const int ct   = w & 7;
    const int kh   = w >> 3;
    const size_t rowbase = (size_t)blockIdx.x * (TILES * ROWST);
    const float4* xblk = (const float4*)(x + rowbase * N_IN);

    const short* wtf = (const short*)(ws + WTF_F);
    const short* wdf = (const short*)(ws + WDF_F);
    const short* wof = (const short*)(ws + WOF_F);

    // ---- prologue LDS copies (all 1024 threads) ----
    for (int idx = tid; idx < 4 * 8 * 512; idx += 1024) wdL[idx] = wdf[idx];
    for (int idx = tid; idx < 4 * 512; idx += 1024)     woL[idx] = wof[idx];
    for (int i = tid; i < 192; i += 1024) {              // zero pad cols 784..807
        int buf = i / 96, rem = i - buf * 96;
        int row = rem / 6, p = rem - row * 6;
        *(uint2*)(&xb16[buf][0] + row * XSTRIDE + 1568 + p * 8) = make_uint2(0u, 0u);
    }

    // ---- weights: split-K frags (kh0: K 0..12, kh1: K 13..24) ----
    bf16x8 wt[13];
    const int k0 = kh * 13;
    #pragma unroll
    for (int i = 0; i < 13; ++i) {
        int K = k0 + i;
        if (K > 24) K = 24;                              // kh1 slot 12 unused (dup)
        wt[i] = *(const bf16x8*)(wtf + (K * 8 + ct) * 512 + lane * 8);
    }
    float bi[4], bd[4], blv[4];
    if (kh == 0) {
        #pragma unroll
        for (int j = 0; j < 4; ++j) {
            int c = 16 * ct + 4 * g + j;
            bi[j] = (c < SD) ? b_in[c] : 0.f;
            bd[j] = ws[BD_F + c];
            int o = 4 * g + j;
            blv[j] = (o < 10) ? ws[BL_F + o] : 0.f;
        }
    }

    // ---- all-thread staging state: 3(+1) float4 per thread ----
    int loff[4];
    #pragma unroll
    for (int q = 0; q < 4; ++q) {
        int idx = tid + 1024 * q;
        int row = idx / 196, col = idx - row * 196;
        if (row > 15) { row = 15; col = 0; }             // q=3, tid>=64: unused
        loff[q] = row * XSTRIDE + col * 8;
    }
    float4 xr[4];

#define STAGE_LOAD(t) do {                                                     \
    const float4* _s = xblk + (size_t)(t) * 3136;                              \
    _Pragma("unroll")                                                          \
    for (int _q = 0; _q < 3; ++_q)                                             \
        xr[_q] = _s[tid + 1024 * _q];                                          \
    if (tid < 64) xr[3] = _s[tid + 3072];                                      \
    __builtin_amdgcn_sched_barrier(0);                                         \
} while (0)

#define STAGE_WRITE(bufp) do {                                                 \
    _Pragma("unroll")                                                          \
    for (int _q = 0; _q < 3; ++_q) {                                           \
        unsigned _u0, _u1;                                                     \
        asm("v_cvt_pk_bf16_f32 %0, %1, %2"                                     \
            : "=v"(_u0) : "v"(xr[_q].x), "v"(xr[_q].y));                       \
        asm("v_cvt_pk_bf16_f32 %0, %1, %2"                                     \
            : "=v"(_u1) : "v"(xr[_q].z), "v"(xr[_q].w));                       \
        *(uint2*)((bufp) + loff[_q]) = make_uint2(_u0, _u1);                   \
    }                                                                          \
    if (tid < 64) {                                                            \
        unsigned _u0, _u1;                                                     \
        asm("v_cvt_pk_bf16_f32 %0, %1, %2"                                     \
            : "=v"(_u0) : "v"(xr[3].x), "v"(xr[3].y));                         \
        asm("v_cvt_pk_bf16_f32 %0, %1, %2"                                     \
            : "=v"(_u1) : "v"(xr[3].z), "v"(xr[3].w));                         \
        *(uint2*)((bufp) + loff[3]) = make_uint2(_u0, _u1);                    \
    }                                                                          \
} while (0)

    // ---- prologue: all threads stage tile 0 ----
    STAGE_LOAD(0);
    STAGE_WRITE(&xb16[0][0]);            // compiler inserts the vmcnt wait
    BAR_LGKM();

    for (int t = 0; t < TILES; ++t) {
        const int cur = t & 1;
        if (t + 1 < TILES) STAGE_LOAD(t + 1);   // issue early (all 16 waves)

        // ---- phase 2 (split-K): all 16 waves ----
        f32x4 acc = (f32x4){0.f, 0.f, 0.f, 0.f};
        {
            const unsigned char* xbr = &xb16[cur][0] + r * XSTRIDE + g * 16;
            if (kh == 0) {
                #pragma unroll
                for (int i = 0; i < 13; ++i) {
                    bf16x8 bf = *(const bf16x8*)(xbr + i * 64);
                    acc = __builtin_amdgcn_mfma_f32_16x16x32_bf16(wt[i], bf, acc, 0, 0, 0);
                }
            } else {
                #pragma unroll
                for (int i = 0; i < 12; ++i) {
                    bf16x8 bf = *(const bf16x8*)(xbr + (13 + i) * 64);
                    acc = __builtin_amdgcn_mfma_f32_16x16x32_bf16(wt[i], bf, acc, 0, 0, 0);
                }
                *(f32x4*)(pL + ct * 1024 + lane * 16) = acc;   // dump partial
            }
        }
        BAR_LGKM();                              // B1: partials sealed; buf cur free

        // ---- all threads: deliver next tile (loads had a full phase to land) ----
        if (t + 1 < TILES) STAGE_WRITE(&xb16[cur ^ 1][0]);

        if (kh == 0) {
            // ---- combine + bias + relu + cvt -> a0b ----
            f32x4 p = *(const f32x4*)(pL + ct * 1024 + lane * 16);
            short* myrow = a0b + r * 136;
            int c0 = 16 * ct + 4 * g;
            float v0 = fmaxf(acc[0] + p[0] + bi[0], 0.f);
            float v1 = fmaxf(acc[1] + p[1] + bi[1], 0.f);
            float v2 = fmaxf(acc[2] + p[2] + bi[2], 0.f);
            float v3 = fmaxf(acc[3] + p[3] + bi[3], 0.f);
            unsigned p01, p23;
            asm("v_cvt_pk_bf16_f32 %0, %1, %2" : "=v"(p01) : "v"(v0), "v"(v1));
            asm("v_cvt_pk_bf16_f32 %0, %1, %2" : "=v"(p23) : "v"(v2), "v"(v3));
            *(uint2*)(myrow + c0) = make_uint2(p01, p23);
        }
        BAR_LGKM();                              // B2: a0b + next x buffer sealed

        if (kh == 0) {
            // ---- phase 3a: acts1 = relu(acts0 @ Wd^T + bd), K=128 ----
            f32x4 acc2 = (f32x4){0.f, 0.f, 0.f, 0.f};
            #pragma unroll
            for (int kk = 0; kk < 4; ++kk) {
                bf16x8 af = *(const bf16x8*)(wdL + (kk * 8 + ct) * 512 + lane * 8);
                bf16x8 bf = *(const bf16x8*)(a0b + r * 136 + kk * 32 + g * 8);
                acc2 = __builtin_amdgcn_mfma_f32_16x16x32_bf16(af, bf, acc2, 0, 0, 0);
            }
            short* myrow = a1b + r * 136;
            int c0 = 16 * ct + 4 * g;
            float v0 = fmaxf(acc2[0] + bd[0], 0.f), v1 = fmaxf(acc2[1] + bd[1], 0.f);
            float v2 = fmaxf(acc2[2] + bd[2], 0.f), v3 = fmaxf(acc2[3] + bd[3], 0.f);
            unsigned p01, p23;
            asm("v_cvt_pk_bf16_f32 %0, %1, %2" : "=v"(p01) : "v"(v0), "v"(v1));
            asm("v_cvt_pk_bf16_f32 %0, %1, %2" : "=v"(p23) : "v"(v2), "v"(v3));
            *(uint2*)(myrow + c0) = make_uint2(p01, p23);
        }
        BAR_LGKM();                              // B3: a1b sealed

        // ---- phase 3b: logits via MFMA + in-register log_softmax + store ----
        if (kh == 0) {
            f32x4 accL = (f32x4){0.f, 0.f, 0.f, 0.f};
            #pragma unroll
            for (int kk = 0; kk < 4; ++kk) {
                bf16x8 af = *(const bf16x8*)(woL + kk * 512 + lane * 8);
                bf16x8 bf = *(const bf16x8*)(a1b + r * 136 + kk * 32 + g * 8);
                accL = __builtin_amdgcn_mfma_f32_16x16x32_bf16(af, bf, accL, 0, 0, 0);
            }
            float lgf[4];
            #pragma unroll
            for (int j = 0; j < 4; ++j)
                lgf[j] = (4 * g + j < 10) ? accL[j] + blv[j] : -1e30f;

            float m = fmaxf(fmaxf(lgf[0], lgf[1]), fmaxf(lgf[2], lgf[3]));
            m = fmaxf(m, __shfl_xor(m, 16, 64));
            m = fmaxf(m, __shfl_xor(m, 32, 64));
            float s = expf(lgf[0] - m) + expf(lgf[1] - m)
                    + expf(lgf[2] - m) + expf(lgf[3] - m);
            s += __shfl_xor(s, 16, 64);
            s += __shfl_xor(s, 32, 64);
            float z = m + logf(s);

            if ((r >> 1) == ct) {                // wave ct stores rows {2ct, 2ct+1}
                float* ob = out + (rowbase + (size_t)t * ROWST + r) * N_OUTS + 4 * g;
                if (g < 3) *(float2*)(ob)     = make_float2(lgf[0] - z, lgf[1] - z);
                if (g < 2) *(float2*)(ob + 2) = make_float2(lgf[2] - z, lgf[3] - z);
            }
        }
        // next-tile hazards sealed by B1/B2/B3.
    }
#undef STAGE_LOAD
#undef STAGE_WRITE
}

extern "C" void kernel_launch(void* const* d_in, const int* in_sizes, int n_in,
                              void* d_out, int out_size, void* d_ws, size_t ws_size,
                              hipStream_t stream) {
    const float* x      = (const float*)d_in[0];
    const float* W_in   = (const float*)d_in[1];
    const float* b_in   = (const float*)d_in[2];
    const float* W_gate = (const float*)d_in[3];
    const float* b_gate = (const float*)d_in[4];
    const float* W_data = (const float*)d_in[5];
    const float* b_data = (const float*)d_in[6];
    const float* W_out  = (const float*)d_in[7];
    const float* b_out  = (const float*)d_in[8];
    float* out = (float*)d_out;
    float* ws  = (float*)d_ws;

    prep_kernel<<<257, 1024, 0, stream>>>(x, W_in, b_in, W_gate, b_gate,
                                          W_data, b_data, W_out, b_out, out, ws);
    main_kernel<<<256, 1024, 0, stream>>>(x, b_in, ws, out);
}